// Round 4
// baseline (164.243 us; speedup 1.0000x reference)
//
#include <hip/hip_runtime.h>
#include <hip/hip_bf16.h>

typedef unsigned short u16;
typedef unsigned int u32;
typedef __bf16 bf16x8 __attribute__((ext_vector_type(8)));
typedef u16 u16x8 __attribute__((ext_vector_type(8)));
typedef float floatx4 __attribute__((ext_vector_type(4)));

#define T_SEQ 2048
#define HDIM 64
#define NBH 32   // B*H

static __device__ __forceinline__ u16 f2b_rne(float x) {
    union { float f; u32 u; } c; c.f = x;
    u32 u = c.u;
    return (u16)((u + 0x7fffu + ((u >> 16) & 1u)) >> 16);
}
static __device__ __forceinline__ u16 f2b_trunc(float x) {
    union { float f; u32 u; } c; c.f = x;
    return (u16)(c.u >> 16);
}

// ---- prepass: K fp32->bf16 flat; V fp32->bf16 transposed [BH,D,T] with
// column permutation pos(k) = tp*32 + qg*8 + u*4 + j  (tp=k>>5, u=(k>>4)&1,
// qg=(k>>2)&3, j=k&3, within each 64-key window) so the 16x16x32 PV B-frag
// (lane quad, elems e=0..7 -> key = tp*32 + (e>>2)*16 + quad*4 + (e&3)) is one
// contiguous 16B read at pos = tp*32 + quad*8. Chunk-preserving. ----
__global__ __launch_bounds__(256) void prep(const float* __restrict__ k,
                                            const float* __restrict__ v,
                                            u16* __restrict__ kb,
                                            u16* __restrict__ vt) {
    __shared__ u16 tile[64][68];
    const int bh = blockIdx.y, t0 = blockIdx.x * 64;
    const int tid = threadIdx.x;

    const float* ksrc = k + ((size_t)bh * T_SEQ + t0) * HDIM;
    u16* kdst = kb + ((size_t)bh * T_SEQ + t0) * HDIM;
#pragma unroll
    for (int p = 0; p < 4; p++) {
        int idx = p * 256 + tid;
        float4 f = ((const float4*)ksrc)[idx];
        ushort4 o;
        o.x = f2b_rne(f.x); o.y = f2b_rne(f.y); o.z = f2b_rne(f.z); o.w = f2b_rne(f.w);
        ((ushort4*)kdst)[idx] = o;
    }

    const float* vsrc = v + ((size_t)bh * T_SEQ + t0) * HDIM;
#pragma unroll
    for (int p = 0; p < 4; p++) {
        int idx = p * 256 + tid;
        int r = idx >> 4, c4 = (idx & 15) * 4;
        float4 f = *(const float4*)(vsrc + r * HDIM + c4);
        tile[c4 + 0][r] = f2b_rne(f.x);
        tile[c4 + 1][r] = f2b_rne(f.y);
        tile[c4 + 2][r] = f2b_rne(f.z);
        tile[c4 + 3][r] = f2b_rne(f.w);
    }
    __syncthreads();
    // 16B stores: pos block pb (8 u16) = keys {tp*32+qg*4+j} u {tp*32+16+qg*4+j}
    u16* dst = vt + (size_t)bh * HDIM * T_SEQ + t0;
#pragma unroll
    for (int p = 0; p < 2; p++) {
        int idx = p * 256 + tid;
        int d = idx >> 3, pb = idx & 7;
        int k0 = (pb >> 2) * 32 + (pb & 3) * 4;
        union { u16x8 v8; ushort4 q[2]; } w;
        w.q[0] = *(ushort4*)&tile[d][k0];
        w.q[1] = *(ushort4*)&tile[d][k0 + 16];
        *(u16x8*)(dst + (size_t)d * T_SEQ + pb * 8) = w.v8;
    }
}

// ---- main kernel ----
// DECOUPLED: no LDS staging, no barriers in the main loop. 1024 blocks x 256
// threads; block = one q-tile (64 rows), 4 waves = (qhalf,khalf) quadrants.
// Each wave loads ITS K fragments (32 keys x 64d = 4KB) and V fragments (4KB,
// prep-permuted so each frag is a contiguous 16B global read) STRAIGHT TO
// REGISTERS, double-buffered: issue tile j+1's 8 loads, compute tile j. The
// compiler inserts counted vmcnt waits; waves drift freely -- the per-iteration
// barrier+staging critical path that pinned rounds 0-3 at ~40us (all pipes
// <30% busy) is gone. Longest blocks launch first (qt = 31 - id>>5); dynamic
// backfill replaces the static balance map. xcd decode keeps 4 bh per XCD
// (2MB K/V, L2-resident). Epilogue: khalf pair-reduce via 20KB LDS, one sync.
__global__ __launch_bounds__(256, 3) void fattn(const float* __restrict__ q,
                                                const u16* __restrict__ kb,
                                                const u16* __restrict__ vtb,
                                                float* __restrict__ out) {
    __shared__ __align__(16) floatx4 xch[2][10][64];   // [qhalf][plane][lane], 20KB

    const int id = blockIdx.x;
    const int xcd = id & 7;
    const int bh = xcd * 4 + ((id >> 3) & 3);          // 4 bh per XCD
    const int qt = 31 - (id >> 5);                     // longest blocks first

    const int tid = threadIdx.x;
    const int wave = tid >> 6, lane = tid & 63;
    const int l15 = lane & 15, quad = lane >> 4;
    const int qhalf = wave >> 1;                       // which 32 q-rows
    const int khalf = wave & 1;                        // which 32 keys
    const int qrow_base = qt * 64 + qhalf * 32;

    const float* qp = q + (size_t)bh * T_SEQ * HDIM;
    const u16* kp = kb + (size_t)bh * T_SEQ * HDIM;
    const u16* vp = vtb + (size_t)bh * HDIM * T_SEQ;

    // per-lane fragment sources (tile j adds j*64 keys):
    // K frag [kc][kb2] <- kp + (j*64 + khalf*32 + kb2*16 + l15)*64 + kc*32 + quad*8
    // V frag [dt]      <- vp + (dt*16 + l15)*T_SEQ + j*64 + khalf*32 + quad*8
    const u16* kg = kp + (khalf * 32 + l15) * HDIM + quad * 8;
    const u16* vg = vp + (size_t)l15 * T_SEQ + khalf * 32 + quad * 8;

    bf16x8 kfA[2][2], kfB[2][2], vfA[4], vfB[4];
    auto load_tiles = [&](int j, bf16x8 (&kf)[2][2], bf16x8 (&vf)[4]) {
        const u16* kj = kg + j * 64 * HDIM;
#pragma unroll
        for (int kc = 0; kc < 2; kc++)
#pragma unroll
            for (int kb2 = 0; kb2 < 2; kb2++)
                kf[kc][kb2] = *(const bf16x8*)(kj + kb2 * 16 * HDIM + kc * 32);
        const u16* vj = vg + j * 64;
#pragma unroll
        for (int dt = 0; dt < 4; dt++)
            vf[dt] = *(const bf16x8*)(vj + dt * 16 * T_SEQ);
    };

    // Q fragments: qf[qb][kc], lane l15 holds Q[qb*16+l15][kc*32+quad*8..+7],
    // pre-scaled by scale*log2(e)
    const float SL2E = 0.125f * 1.44269504088896f;
    bf16x8 qf[2][2];
#pragma unroll
    for (int qb = 0; qb < 2; qb++) {
        const float* qrow = qp + (size_t)(qrow_base + qb * 16 + l15) * HDIM;
#pragma unroll
        for (int kc = 0; kc < 2; kc++) {
            const float4* p4 = (const float4*)(qrow + kc * 32 + quad * 8);
            float4 fa = p4[0], fb = p4[1];
            union { bf16x8 v; u16 s[8]; } cv;
            cv.s[0] = f2b_rne(fa.x * SL2E); cv.s[1] = f2b_rne(fa.y * SL2E);
            cv.s[2] = f2b_rne(fa.z * SL2E); cv.s[3] = f2b_rne(fa.w * SL2E);
            cv.s[4] = f2b_rne(fb.x * SL2E); cv.s[5] = f2b_rne(fb.y * SL2E);
            cv.s[6] = f2b_rne(fb.z * SL2E); cv.s[7] = f2b_rne(fb.w * SL2E);
            qf[qb][kc] = cv.v;
        }
    }

    // all-ones bf16 B-frag for MFMA row-sums
    union { u16 h[8]; bf16x8 v; } onesu;
#pragma unroll
    for (int i = 0; i < 8; i++) onesu.h[i] = 0x3F80;
    const bf16x8 ones = onesu.v;

    floatx4 o_acc[2][4];                               // [qb][dt], partial (khalf)
    floatx4 lsacc[2];                                  // [qb] partial row-sums
#pragma unroll
    for (int qb = 0; qb < 2; qb++) {
        lsacc[qb] = (floatx4){0.f, 0.f, 0.f, 0.f};
#pragma unroll
        for (int dt = 0; dt < 4; dt++) o_acc[qb][dt] = (floatx4){0.f, 0.f, 0.f, 0.f};
    }

    auto compute = [&](int j, bf16x8 (&kf)[2][2], bf16x8 (&vf)[4]) {
        // S^T quadrant = K(32 own keys) . Q^T(32 own q): 8 MFMA
        floatx4 sacc[2][2];                            // [kb2][qb]
#pragma unroll
        for (int kb2 = 0; kb2 < 2; kb2++)
#pragma unroll
            for (int qb = 0; qb < 2; qb++) sacc[kb2][qb] = (floatx4){0.f, 0.f, 0.f, 0.f};
        __builtin_amdgcn_s_setprio(1);
#pragma unroll
        for (int kc = 0; kc < 2; kc++)
#pragma unroll
            for (int kb2 = 0; kb2 < 2; kb2++)
#pragma unroll
                for (int qb = 0; qb < 2; qb++)
                    sacc[kb2][qb] = __builtin_amdgcn_mfma_f32_16x16x32_bf16(
                        kf[kc][kb2], qf[qb][kc], sacc[kb2][qb], 0, 0, 0);
        __builtin_amdgcn_s_setprio(0);

        // P^T = exp2(S^T); causal mask only on the diagonal tile; pack into
        // PV A-frags: elem e = kb2*4+rg <-> key khalf*32 + kb2*16 + quad*4 + rg
        union { bf16x8 v; u16 h[8]; } pk[2];
        if (j == qt) {
            const int key0 = khalf * 32 + quad * 4;
#pragma unroll
            for (int qb = 0; qb < 2; qb++) {
                const int gq = qhalf * 32 + qb * 16 + l15;
#pragma unroll
                for (int kb2 = 0; kb2 < 2; kb2++)
#pragma unroll
                    for (int rg = 0; rg < 4; rg++) {
                        float e = __builtin_amdgcn_exp2f(sacc[kb2][qb][rg]);
                        if (key0 + kb2 * 16 + rg > gq) e = 0.f;
                        pk[qb].h[kb2 * 4 + rg] = f2b_trunc(e);
                    }
            }
        } else {
#pragma unroll
            for (int qb = 0; qb < 2; qb++)
#pragma unroll
                for (int kb2 = 0; kb2 < 2; kb2++)
#pragma unroll
                    for (int rg = 0; rg < 4; rg++)
                        pk[qb].h[kb2 * 4 + rg] =
                            f2b_trunc(__builtin_amdgcn_exp2f(sacc[kb2][qb][rg]));
        }

        // O_partial += P . V (8 MFMA) ; row-sums += P . ones (2 MFMA)
        __builtin_amdgcn_s_setprio(1);
#pragma unroll
        for (int dt = 0; dt < 4; dt++)
#pragma unroll
            for (int qb = 0; qb < 2; qb++)
                o_acc[qb][dt] = __builtin_amdgcn_mfma_f32_16x16x32_bf16(
                    pk[qb].v, vf[dt], o_acc[qb][dt], 0, 0, 0);
        lsacc[0] = __builtin_amdgcn_mfma_f32_16x16x32_bf16(pk[0].v, ones, lsacc[0], 0, 0, 0);
        lsacc[1] = __builtin_amdgcn_mfma_f32_16x16x32_bf16(pk[1].v, ones, lsacc[1], 0, 0, 0);
        __builtin_amdgcn_s_setprio(0);
    };

    // software-pipelined main loop, register double-buffer, no barriers
    load_tiles(0, kfA, vfA);
    for (int j = 0; j <= qt; j += 2) {
        if (j + 1 <= qt) load_tiles(j + 1, kfB, vfB);
        compute(j, kfA, vfA);
        if (j + 1 > qt) break;
        if (j + 2 <= qt) load_tiles(j + 2, kfA, vfA);
        compute(j + 1, kfB, vfB);
    }

    // ---- epilogue: khalf pair-reduce via LDS, normalize, store ----
    // lsacc[qb][rg] = partial row-sum for q = qrow_base + qb*16 + quad*4 + rg
    // (identical across l15) -- exactly o_acc's row indexing.
    floatx4 (*xv)[64] = xch[qhalf];
    if (khalf == 0) {
#pragma unroll
        for (int qb = 0; qb < 2; qb++)
#pragma unroll
            for (int dt = 0; dt < 4; dt++) xv[qb * 4 + dt][lane] = o_acc[qb][dt];
        xv[8][lane] = lsacc[0];
        xv[9][lane] = lsacc[1];
    }
    __syncthreads();
    if (khalf == 1) {
        float* op = out + (size_t)bh * T_SEQ * HDIM;
#pragma unroll
        for (int qb = 0; qb < 2; qb++) {
#pragma unroll
            for (int dt = 0; dt < 4; dt++) o_acc[qb][dt] += xv[qb * 4 + dt][lane];
            lsacc[qb] += xv[8 + qb][lane];
#pragma unroll
            for (int rg = 0; rg < 4; rg++) {
                float inv = 1.0f / lsacc[qb][rg];
                size_t row = (size_t)(qrow_base + qb * 16 + quad * 4 + rg) * HDIM;
#pragma unroll
                for (int dt = 0; dt < 4; dt++)
                    op[row + dt * 16 + l15] = o_acc[qb][dt][rg] * inv;
            }
        }
    }
}

extern "C" void kernel_launch(void* const* d_in, const int* in_sizes, int n_in,
                              void* d_out, int out_size, void* d_ws, size_t ws_size,
                              hipStream_t stream) {
    const float* q = (const float*)d_in[0];
    const float* k = (const float*)d_in[1];
    const float* v = (const float*)d_in[2];
    float* out = (float*)d_out;

    u16* kb = (u16*)d_ws;                               // 8 MB bf16 K
    u16* vt = kb + (size_t)NBH * T_SEQ * HDIM;          // 8 MB bf16 V^T (permuted)

    prep<<<dim3(T_SEQ / 64, NBH), 256, 0, stream>>>(k, v, kb, vt);
    fattn<<<dim3(1024), 256, 0, stream>>>(q, kb, vt, out);
}

// Round 5
// 124.193 us; speedup vs baseline: 1.3225x; 1.3225x over previous
//
#include <hip/hip_runtime.h>
#include <hip/hip_bf16.h>

typedef unsigned short u16;
typedef unsigned int u32;
typedef __bf16 bf16x8 __attribute__((ext_vector_type(8)));
typedef u16 u16x8 __attribute__((ext_vector_type(8)));
typedef float floatx4 __attribute__((ext_vector_type(4)));

#define T_SEQ 2048
#define HDIM 64
#define NBH 32   // B*H

static __device__ __forceinline__ u16 f2b_rne(float x) {
    union { float f; u32 u; } c; c.f = x;
    u32 u = c.u;
    return (u16)((u + 0x7fffu + ((u >> 16) & 1u)) >> 16);
}
static __device__ __forceinline__ u16 f2b_trunc(float x) {
    union { float f; u32 u; } c; c.f = x;
    return (u16)(c.u >> 16);
}

// async 16B/lane global->LDS; LDS dest = wave-uniform base + lane*16
#define GLOAD_LDS16(gp, lp)                                                      \
    __builtin_amdgcn_global_load_lds(                                            \
        (const __attribute__((address_space(1))) u32*)(gp),                      \
        (__attribute__((address_space(3))) u32*)(lp), 16, 0, 0)

// counted vmem waits (wait until <= N vmem ops outstanding)
#define WAIT_VM(N) asm volatile("s_waitcnt vmcnt(" #N ")" ::: "memory")

// ---- prepass: K fp32->bf16 flat; V fp32->bf16 transposed [BH,D,T] with
// column permutation pos(k) = tp*32 + qg*8 + u*4 + j  (tp=k>>5, u=(k>>4)&1,
// qg=(k>>2)&3, j=k&3, within each 64-key window) so the 16x16x32 PV B-frag
// (lane quad, elems e=0..7 -> key = tp*32 + (e>>2)*16 + quad*4 + (e&3)) is one
// contiguous 16B read at pos = tp*32 + quad*8. Chunk-preserving. ----
__global__ __launch_bounds__(256) void prep(const float* __restrict__ k,
                                            const float* __restrict__ v,
                                            u16* __restrict__ kb,
                                            u16* __restrict__ vt) {
    __shared__ u16 tile[64][68];
    const int bh = blockIdx.y, t0 = blockIdx.x * 64;
    const int tid = threadIdx.x;

    const float* ksrc = k + ((size_t)bh * T_SEQ + t0) * HDIM;
    u16* kdst = kb + ((size_t)bh * T_SEQ + t0) * HDIM;
#pragma unroll
    for (int p = 0; p < 4; p++) {
        int idx = p * 256 + tid;
        float4 f = ((const float4*)ksrc)[idx];
        ushort4 o;
        o.x = f2b_rne(f.x); o.y = f2b_rne(f.y); o.z = f2b_rne(f.z); o.w = f2b_rne(f.w);
        ((ushort4*)kdst)[idx] = o;
    }

    const float* vsrc = v + ((size_t)bh * T_SEQ + t0) * HDIM;
#pragma unroll
    for (int p = 0; p < 4; p++) {
        int idx = p * 256 + tid;
        int r = idx >> 4, c4 = (idx & 15) * 4;
        float4 f = *(const float4*)(vsrc + r * HDIM + c4);
        tile[c4 + 0][r] = f2b_rne(f.x);
        tile[c4 + 1][r] = f2b_rne(f.y);
        tile[c4 + 2][r] = f2b_rne(f.z);
        tile[c4 + 3][r] = f2b_rne(f.w);
    }
    __syncthreads();
    // 16B stores: pos block pb (8 u16) = keys {tp*32+qg*4+j} u {tp*32+16+qg*4+j}
    u16* dst = vt + (size_t)bh * HDIM * T_SEQ + t0;
#pragma unroll
    for (int p = 0; p < 2; p++) {
        int idx = p * 256 + tid;
        int d = idx >> 3, pb = idx & 7;
        int k0 = (pb >> 2) * 32 + (pb & 3) * 4;
        union { u16x8 v8; ushort4 q[2]; } w;
        w.q[0] = *(ushort4*)&tile[d][k0];
        w.q[1] = *(ushort4*)&tile[d][k0 + 16];
        *(u16x8*)(dst + (size_t)d * T_SEQ + pb * 8) = w.v8;
    }
}

// ---- main kernel ----
// 512 blocks x 256 threads (4 waves). Decode: xcd=id&7 -> 4 distinct bh per
// XCD (2MB K/V, L2-resident). Block owns q-tile pair (qtHi=31-pr, qtLo=pr);
// wave = (tile_sel=wave>>1, khalf=wave&1). QHALF-FUSED: each wave computes its
// 32-key strip against ALL 64 q-rows of its tile (o_acc 64 VGPR). Per tile-
// stage each K/V byte is read from LDS by exactly ONE wave per tile-group:
// LDS reads 1.05MB/CU (was 2.1 r3, 4.2 r0-r2), wave-iters halve to 132/CU,
// barriers rendezvous 4 waves not 8, and each compute phase has 2x the
// independent ops (16 MFMA / 32 exp2) to hide its own latency. Staging ring,
// swizzles, V-permutation identical to r3 (4 GLOADs/wave/tile -> vmcnt 8/4/0).
// Epilogue: khalf pair-reduce via LDS (20KB region per tile-group), two syncs.
__global__ __launch_bounds__(256, 2) void fattn(const float* __restrict__ q,
                                                const u16* __restrict__ kb,
                                                const u16* __restrict__ vtb,
                                                float* __restrict__ out) {
    __shared__ __align__(16) u16 Kl[4][64 * 64];   // [key][d], XOR slot swizzle
    __shared__ __align__(16) u16 Vl[4][64 * 64];   // [d][perm-key], +d slot swizzle

    const int id = blockIdx.x;
    const int xcd = id & 7;
    const int u = id >> 3;                         // 0..63
    const int bh = xcd * 4 + (u & 3);              // 4 bh per XCD
    const int s = u >> 2;                          // 0..15
    const int pr = (s & 8) ? (s ^ 7) : s;          // cousin map: CU pairs (s,15-s)
    const int qtHi = 31 - pr, qtLo = pr;

    const int tid = threadIdx.x;
    const int wave = tid >> 6, lane = tid & 63;
    const int l15 = lane & 15, quad = lane >> 4;
    const int tile_sel = wave >> 1;                // 0: hi tile, 1: lo tile
    const int khalf = wave & 1;                    // which 32 keys
    const int qt = tile_sel ? qtLo : qtHi;
    const int qrow_base = qt * 64;                 // wave covers all 64 q-rows

    const float* qp = q + (size_t)bh * T_SEQ * HDIM;
    const u16* kp = kb + (size_t)bh * T_SEQ * HDIM;
    const u16* vp = vtb + (size_t)bh * HDIM * T_SEQ;

    // staging: 4 waves cover the 64-row K tile + 64-row V^T tile, two 16B
    // GLOADs each per array (4 vmem/wave/tile). lane covers rows
    // srow = wave*16 + (lane>>3) (+8 for the second GLOAD; (srow+8)&7==srow&7
    // so the same swizzled source pointer works), slot = lane&7. Source picked
    // so LDS slot b at row r holds: K block b^(r&7); V perm-slot (b-r)&7.
    const int srow = wave * 16 + (lane >> 3);
    const int slot = lane & 7;
    const u16* kg0 = kp + srow * HDIM + (slot ^ (srow & 7)) * 8;
    const u16* vg0 = vp + (size_t)srow * T_SEQ + ((slot - srow) & 7) * 8;

    auto stage = [&](int j, int buf) {
        const u16* ks = kg0 + j * 64 * HDIM;
        u16* Kd = &Kl[buf][wave * 1024];
        GLOAD_LDS16(ks, Kd);
        GLOAD_LDS16(ks + 8 * HDIM, Kd + 512);
        const u16* vs2 = vg0 + j * 64;
        u16* Vd = &Vl[buf][wave * 1024];
        GLOAD_LDS16(vs2, Vd);
        GLOAD_LDS16(vs2 + 8 * T_SEQ, Vd + 512);
    };

    // Q fragments: qf[qb][kc], lane l15 holds Q[qb*16+l15][kc*32+quad*8..+7],
    // pre-scaled by scale*log2(e). Loaded before the pipeline prologue.
    const float SL2E = 0.125f * 1.44269504088896f;
    bf16x8 qf[4][2];
#pragma unroll
    for (int qb = 0; qb < 4; qb++) {
        const float* qrow = qp + (size_t)(qrow_base + qb * 16 + l15) * HDIM;
#pragma unroll
        for (int kc = 0; kc < 2; kc++) {
            const float4* p4 = (const float4*)(qrow + kc * 32 + quad * 8);
            float4 fa = p4[0], fb = p4[1];
            union { bf16x8 v; u16 s[8]; } cv;
            cv.s[0] = f2b_rne(fa.x * SL2E); cv.s[1] = f2b_rne(fa.y * SL2E);
            cv.s[2] = f2b_rne(fa.z * SL2E); cv.s[3] = f2b_rne(fa.w * SL2E);
            cv.s[4] = f2b_rne(fb.x * SL2E); cv.s[5] = f2b_rne(fb.y * SL2E);
            cv.s[6] = f2b_rne(fb.z * SL2E); cv.s[7] = f2b_rne(fb.w * SL2E);
            qf[qb][kc] = cv.v;
        }
    }

    // all-ones bf16 B-frag for MFMA row-sums
    union { u16 h[8]; bf16x8 v; } onesu;
#pragma unroll
    for (int i = 0; i < 8; i++) onesu.h[i] = 0x3F80;
    const bf16x8 ones = onesu.v;

    // pipeline prologue: 3 tiles in flight (qtHi >= 16 always)
    stage(0, 0);
    stage(1, 1);
    stage(2, 2);

    floatx4 o_acc[4][4];                           // [qb][dt], partial (khalf)
    floatx4 lsacc[4];                              // [qb] partial row-sums
#pragma unroll
    for (int qb = 0; qb < 4; qb++) {
        lsacc[qb] = (floatx4){0.f, 0.f, 0.f, 0.f};
#pragma unroll
        for (int dt = 0; dt < 4; dt++) o_acc[qb][dt] = (floatx4){0.f, 0.f, 0.f, 0.f};
    }

    for (int j = 0; j <= qtHi; ++j) {
        // counted waits: tile j's 4 loads done, tiles j+1,j+2 stay in flight
        if (j + 2 <= qtHi)      WAIT_VM(8);
        else if (j + 1 <= qtHi) WAIT_VM(4);
        else                    WAIT_VM(0);
        __builtin_amdgcn_s_barrier();              // all waves' tile-j in LDS

        const int cur = j & 3;
        const bool active = (j <= qt);             // wave-uniform

        // K fragments for this wave's 32 keys (4KB): read before next stage
        bf16x8 kf[2][2];                           // [kc][kb2]
        if (active) {
            const u16* Kc = Kl[cur];
#pragma unroll
            for (int kc = 0; kc < 2; kc++)
#pragma unroll
                for (int kb2 = 0; kb2 < 2; kb2++) {
                    int rk = khalf * 32 + kb2 * 16 + l15;
                    kf[kc][kb2] = *(const bf16x8*)(Kc + rk * 64 + ((kc * 4 + quad) ^ (rk & 7)) * 8);
                }
        }
        if (j + 3 <= qtHi) stage(j + 3, (j + 3) & 3);  // async prefetch, 3 ahead
        if (!active) continue;

        // S^T strip = K(32 own keys) . Q^T(64 q): 16 MFMA, 8 indep chains
        floatx4 sacc[2][4];                        // [kb2][qb]
#pragma unroll
        for (int kb2 = 0; kb2 < 2; kb2++)
#pragma unroll
            for (int qb = 0; qb < 4; qb++) sacc[kb2][qb] = (floatx4){0.f, 0.f, 0.f, 0.f};
        __builtin_amdgcn_s_setprio(1);
#pragma unroll
        for (int kc = 0; kc < 2; kc++)
#pragma unroll
            for (int kb2 = 0; kb2 < 2; kb2++)
#pragma unroll
                for (int qb = 0; qb < 4; qb++)
                    sacc[kb2][qb] = __builtin_amdgcn_mfma_f32_16x16x32_bf16(
                        kf[kc][kb2], qf[qb][kc], sacc[kb2][qb], 0, 0, 0);
        __builtin_amdgcn_s_setprio(0);

        // P^T = exp2(S^T); causal mask only on the diagonal tile; pack into
        // PV A-frags: elem e = kb2*4+rg <-> key khalf*32 + kb2*16 + quad*4 + rg
        union { bf16x8 v; u16 h[8]; } pk[4];
        if (j == qt) {
            const int key0 = khalf * 32 + quad * 4;
#pragma unroll
            for (int qb = 0; qb < 4; qb++) {
                const int gq = qb * 16 + l15;
#pragma unroll
                for (int kb2 = 0; kb2 < 2; kb2++)
#pragma unroll
                    for (int rg = 0; rg < 4; rg++) {
                        float e = __builtin_amdgcn_exp2f(sacc[kb2][qb][rg]);
                        if (key0 + kb2 * 16 + rg > gq) e = 0.f;
                        pk[qb].h[kb2 * 4 + rg] = f2b_trunc(e);
                    }
            }
        } else {
#pragma unroll
            for (int qb = 0; qb < 4; qb++)
#pragma unroll
                for (int kb2 = 0; kb2 < 2; kb2++)
#pragma unroll
                    for (int rg = 0; rg < 4; rg++)
                        pk[qb].h[kb2 * 4 + rg] =
                            f2b_trunc(__builtin_amdgcn_exp2f(sacc[kb2][qb][rg]));
        }

        // V fragments for this wave's 32 keys (4KB), chunk tp = khalf
        const u16* Vc = Vl[cur];
        bf16x8 vf[4];
#pragma unroll
        for (int dt = 0; dt < 4; dt++) {
            int d = dt * 16 + l15;
            vf[dt] = *(const bf16x8*)(Vc + d * 64 + ((khalf * 4 + quad + d) & 7) * 8);
        }

        // O_partial += P . V (16 MFMA, indep) ; row-sums += P . ones (4 MFMA)
        __builtin_amdgcn_s_setprio(1);
#pragma unroll
        for (int dt = 0; dt < 4; dt++)
#pragma unroll
            for (int qb = 0; qb < 4; qb++)
                o_acc[qb][dt] = __builtin_amdgcn_mfma_f32_16x16x32_bf16(
                    pk[qb].v, vf[dt], o_acc[qb][dt], 0, 0, 0);
#pragma unroll
        for (int qb = 0; qb < 4; qb++)
            lsacc[qb] = __builtin_amdgcn_mfma_f32_16x16x32_bf16(pk[qb].v, ones, lsacc[qb], 0, 0, 0);
        __builtin_amdgcn_s_setprio(0);
    }

    // ---- epilogue: khalf pair-reduce via LDS, normalize, store ----
    // lsacc[qb][rg] = partial row-sum for q = qrow_base + qb*16 + quad*4 + rg
    // (identical across l15) -- exactly o_acc's row indexing. Per tile-group
    // region: 20 planes x 64 lanes x 16B = 20KB (tile 0 -> Kl, tile 1 -> Vl).
    __syncthreads();                               // main-loop LDS use complete
    floatx4* xv = (floatx4*)(tile_sel ? (void*)&Vl[0][0] : (void*)&Kl[0][0]);
    if (khalf == 0) {
#pragma unroll
        for (int qb = 0; qb < 4; qb++) {
#pragma unroll
            for (int dt = 0; dt < 4; dt++) xv[(qb * 4 + dt) * 64 + lane] = o_acc[qb][dt];
            xv[(16 + qb) * 64 + lane] = lsacc[qb];
        }
    }
    __syncthreads();
    if (khalf == 1) {
        float* op = out + (size_t)bh * T_SEQ * HDIM;
#pragma unroll
        for (int qb = 0; qb < 4; qb++) {
#pragma unroll
            for (int dt = 0; dt < 4; dt++) o_acc[qb][dt] += xv[(qb * 4 + dt) * 64 + lane];
            lsacc[qb] += xv[(16 + qb) * 64 + lane];
#pragma unroll
            for (int rg = 0; rg < 4; rg++) {
                float inv = 1.0f / lsacc[qb][rg];
                size_t row = (size_t)(qrow_base + qb * 16 + quad * 4 + rg) * HDIM;
#pragma unroll
                for (int dt = 0; dt < 4; dt++)
                    op[row + dt * 16 + l15] = o_acc[qb][dt][rg] * inv;
            }
        }
    }
}

extern "C" void kernel_launch(void* const* d_in, const int* in_sizes, int n_in,
                              void* d_out, int out_size, void* d_ws, size_t ws_size,
                              hipStream_t stream) {
    const float* q = (const float*)d_in[0];
    const float* k = (const float*)d_in[1];
    const float* v = (const float*)d_in[2];
    float* out = (float*)d_out;

    u16* kb = (u16*)d_ws;                               // 8 MB bf16 K
    u16* vt = kb + (size_t)NBH * T_SEQ * HDIM;          // 8 MB bf16 V^T (permuted)

    prep<<<dim3(T_SEQ / 64, NBH), 256, 0, stream>>>(k, v, kb, vt);
    fattn<<<dim3(512), 256, 0, stream>>>(q, kb, vt, out);
}